// Round 2
// baseline (443.829 us; speedup 1.0000x reference)
//
#include <hip/hip_runtime.h>
#include <hip/hip_fp16.h>
#include <math.h>

#define BATCH 16
#define CIN   128
#define LIN   8192
#define COUT  128
#define LOUT  16384
#define KEXP  768          // 2 shift-halves * (3 powers * 128 channels)
#define NT    128          // i-tile width
#define NTILES (LIN/NT)    // 64
#define PCOLS 130          // i0-1 .. i0+128 inclusive
#define PCPAD 136          // c-dim padded: 272B row stride -> even bank spread, 16B aligned
#define PSZ   (PCOLS*PCPAD)

typedef _Float16 f16x8 __attribute__((ext_vector_type(8)));
typedef float    f32x4 __attribute__((ext_vector_type(4)));

// ---------------- weight prep: fold taps, cast to fp16 ----------------
// WE[co][k]: k<384 -> W[co][k][0] (pairs with P[.,i-1]);  k>=384 -> W1+W2 (pairs with P[.,i])
// WO[co][k]: k<384 -> W0+W1      (pairs with P[.,i]);    k>=384 -> W2    (pairs with P[.,i+1])
__global__ void prep_weights(const float* __restrict__ W,
                             _Float16* __restrict__ WE,
                             _Float16* __restrict__ WO) {
  int idx = blockIdx.x * 256 + threadIdx.x;       // 128*768 total
  int co = idx / KEXP;
  int k  = idx % KEXP;
  int cq = (k < 384) ? k : k - 384;   // R1 fix: 384 is NOT a power of two; k&383 was wrong
  const float* w = W + ((size_t)co * 384 + cq) * 3;
  float we, wo;
  if (k < 384) { we = w[0];        wo = w[0] + w[1]; }
  else         { we = w[1] + w[2]; wo = w[2];        }
  WE[(size_t)co * KEXP + k] = (_Float16)we;
  WO[(size_t)co * KEXP + k] = (_Float16)wo;
}

// ---------------- fused conv GEMM (E and O), stats accumulation ----------------
__launch_bounds__(256, 1)
__global__ void conv_gemm(const float* __restrict__ x,
                          const _Float16* __restrict__ WE,
                          const _Float16* __restrict__ WO,
                          float* __restrict__ out,
                          float* __restrict__ stats) {
  extern __shared__ char smem_raw[];
  _Float16* plane  = (_Float16*)smem_raw;                  // [3][PCOLS][PCPAD]
  float*    sstats = (float*)(smem_raw + 3 * PSZ * 2);     // [128][2]

  const int tile = blockIdx.x;        // 0..63
  const int b    = blockIdx.y;        // 0..15
  const int i0   = tile * NT;
  const int t    = threadIdx.x;
  const int lane = t & 63;
  const int wave = t >> 6;            // 4 waves, 2x2 over (co, n): wave tile 64x64
  const int wm   = wave >> 1, wn = wave & 1;
  const int l15  = lane & 15, quad = lane >> 4;

  if (t < 128) { sstats[2 * t] = 0.f; sstats[2 * t + 1] = 0.f; }

  // --- build power planes: plane[q][col][c] = x[b,c,i0-1+col]^(q+1), fp16 ---
  const float* xb = x + (size_t)b * CIN * LIN;
  for (int idx = t; idx < CIN * PCOLS; idx += 256) {
    int c   = idx / PCOLS;
    int col = idx - c * PCOLS;                  // consecutive t -> consecutive col (coalesced x reads)
    int gi  = i0 - 1 + col;
    float v = (gi >= 0 && gi < LIN) ? xb[(size_t)c * LIN + gi] : 0.f;
    float v2 = v * v;
    int base = col * PCPAD + c;
    plane[base]            = (_Float16)v;
    plane[PSZ + base]      = (_Float16)v2;
    plane[2 * PSZ + base]  = (_Float16)(v2 * v);
  }
  __syncthreads();

  f32x4 accE[4][4], accO[4][4];
  const f32x4 zero = {0.f, 0.f, 0.f, 0.f};
#pragma unroll
  for (int fm = 0; fm < 4; ++fm)
#pragma unroll
    for (int fn = 0; fn < 4; ++fn) { accE[fm][fn] = zero; accO[fm][fn] = zero; }

  const int mbase = wm * 64 + l15;    // A row (add fm*16)
  const int kl    = quad * 8;         // k-within-step for this lane

  // --- barrier-free K loop: 24 steps of 32 ---
  for (int ks = 0; ks < 24; ++ks) {
    const int K0 = ks * 32;
    const int q  = (ks % 12) >> 2;              // power plane
    const int cb = (ks & 3) * 32;               // channel base
    const int sE = (ks < 12) ? 0 : 1;           // local col offset for E (O = sE+1)
    const _Float16* pb = plane + q * PSZ + cb + kl;

    f16x8 bE[4], bO[4];
#pragma unroll
    for (int fn = 0; fn < 4; ++fn) {
      int colE = wn * 64 + fn * 16 + l15 + sE;
      bE[fn] = *(const f16x8*)(pb + colE * PCPAD);
      bO[fn] = *(const f16x8*)(pb + (colE + 1) * PCPAD);
    }
    f16x8 aE[4], aO[4];
#pragma unroll
    for (int fm = 0; fm < 4; ++fm) {
      int row = mbase + fm * 16;
      aE[fm] = *(const f16x8*)(WE + (size_t)row * KEXP + K0 + kl);
      aO[fm] = *(const f16x8*)(WO + (size_t)row * KEXP + K0 + kl);
    }
#pragma unroll
    for (int fm = 0; fm < 4; ++fm)
#pragma unroll
      for (int fn = 0; fn < 4; ++fn) {
        accE[fm][fn] = __builtin_amdgcn_mfma_f32_16x16x32_f16(aE[fm], bE[fn], accE[fm][fn], 0, 0, 0);
        accO[fm][fn] = __builtin_amdgcn_mfma_f32_16x16x32_f16(aO[fm], bO[fn], accO[fm][fn], 0, 0, 0);
      }
  }

  // --- epilogue: stats + interleaved stores ---
  // C/D layout: n = lane&15, m = quad*4 + r
  float* orow_base = out + (size_t)b * COUT * LOUT;
#pragma unroll
  for (int fm = 0; fm < 4; ++fm) {
#pragma unroll
    for (int r = 0; r < 4; ++r) {
      float s1 = 0.f, s2 = 0.f;
#pragma unroll
      for (int fn = 0; fn < 4; ++fn) {
        float vE = accE[fm][fn][r], vO = accO[fm][fn][r];
        s1 += vE + vO;
        s2 += vE * vE + vO * vO;
      }
#pragma unroll
      for (int off = 8; off >= 1; off >>= 1) {
        s1 += __shfl_xor(s1, off, 64);
        s2 += __shfl_xor(s2, off, 64);
      }
      int co = wm * 64 + fm * 16 + quad * 4 + r;
      if (l15 == 0) {
        atomicAdd(&sstats[2 * co], s1);
        atomicAdd(&sstats[2 * co + 1], s2);
      }
      float* orow = orow_base + (size_t)co * LOUT;
#pragma unroll
      for (int fn = 0; fn < 4; ++fn) {
        int n = i0 + wn * 64 + fn * 16 + l15;
        float2 v = make_float2(accE[fm][fn][r], accO[fm][fn][r]);
        *(float2*)(orow + 2 * n) = v;   // even=E, odd=O, coalesced 128B
      }
    }
  }
  __syncthreads();
  if (t < 128) {
    atomicAdd(&stats[((size_t)b * COUT + t) * 2],     sstats[2 * t]);
    atomicAdd(&stats[((size_t)b * COUT + t) * 2 + 1], sstats[2 * t + 1]);
  }
}

// ---------------- instance norm + tanh, in place ----------------
__device__ inline float tanh_fast(float z) {
  float e = __expf(2.f * z);
  return 1.f - 2.f / (e + 1.f);   // saturates correctly for |z| large
}

__global__ void norm_tanh(float* __restrict__ out, const float* __restrict__ stats) {
  int row = blockIdx.x;                         // b*128 + co
  float s1 = stats[2 * row], s2 = stats[2 * row + 1];
  const float invN = 1.f / (float)LOUT;
  float mean = s1 * invN;
  float var  = fmaxf(s2 * invN - mean * mean, 0.f);
  float inv  = rsqrtf(var + 1e-5f);
  float4* p = (float4*)(out + (size_t)row * LOUT);
  for (int i = threadIdx.x; i < LOUT / 4; i += 256) {
    float4 v = p[i];
    v.x = tanh_fast((v.x - mean) * inv);
    v.y = tanh_fast((v.y - mean) * inv);
    v.z = tanh_fast((v.z - mean) * inv);
    v.w = tanh_fast((v.w - mean) * inv);
    p[i] = v;
  }
}

extern "C" void kernel_launch(void* const* d_in, const int* in_sizes, int n_in,
                              void* d_out, int out_size, void* d_ws, size_t ws_size,
                              hipStream_t stream) {
  const float* x = (const float*)d_in[0];
  const float* W = (const float*)d_in[1];
  // d_in[2] = bias: a per-(b,co) constant, exactly cancelled by InstanceNorm -> unused.
  float* out = (float*)d_out;

  // ws layout: [0,16K) stats f32[16][128][2]; then WE f16[128][768]; then WO
  float*    stats = (float*)d_ws;
  _Float16* WE    = (_Float16*)((char*)d_ws + 16384);
  _Float16* WO    = WE + (size_t)COUT * KEXP;

  hipMemsetAsync(d_ws, 0, 16384, stream);
  prep_weights<<<dim3((COUT * KEXP) / 256), dim3(256), 0, stream>>>(W, WE, WO);

  size_t shmem = (size_t)3 * PSZ * 2 + 128 * 2 * sizeof(float);  // 107,104 B
  hipFuncSetAttribute(reinterpret_cast<const void*>(conv_gemm),
                      hipFuncAttributeMaxDynamicSharedMemorySize, (int)shmem);
  conv_gemm<<<dim3(NTILES, BATCH), dim3(256), shmem, stream>>>(x, WE, WO, out, stats);

  norm_tanh<<<dim3(BATCH * COUT), dim3(256), 0, stream>>>(out, stats);
}

// Round 3
// 328.550 us; speedup vs baseline: 1.3509x; 1.3509x over previous
//
#include <hip/hip_runtime.h>
#include <hip/hip_fp16.h>
#include <math.h>

#define BATCH 16
#define CIN   128
#define LIN   8192
#define COUT  128
#define LOUT  16384
#define KEXP  768          // 2 shift-halves * (3 powers * 128 channels)
#define NT    128          // i-tile width
#define NTILES (LIN/NT)    // 64
#define PCOLS 130          // i0-1 .. i0+128 inclusive
#define PCPAD 136          // halfwords per col; 272B stride, 16B aligned
#define PSZ   (PCOLS*PCPAD)

typedef _Float16 f16x8 __attribute__((ext_vector_type(8)));
typedef float    f32x4 __attribute__((ext_vector_type(4)));

// ---------------- weight prep: fold taps, cast fp16, FRAG-MAJOR swizzle ----------------
// Frag layout: element (co, k) -> WE[((mtile*24 + ks)*64 + quad*16 + l15)*8 + j]
//   mtile=co>>4, l15=co&15, ks=k>>5, quad=(k&31)>>3, j=k&7
// so one A-frag load = uniform base + lane*16B (contiguous 1KB).
__global__ void prep_weights(const float* __restrict__ W,
                             _Float16* __restrict__ WE,
                             _Float16* __restrict__ WO) {
  int idx = blockIdx.x * 256 + threadIdx.x;       // 128*768 total
  int co = idx / KEXP;
  int k  = idx % KEXP;
  int cq = (k < 384) ? k : k - 384;               // 384 is NOT a power of two
  const float* w = W + ((size_t)co * 384 + cq) * 3;
  float we, wo;
  if (k < 384) { we = w[0];        wo = w[0] + w[1]; }
  else         { we = w[1] + w[2]; wo = w[2];        }
  int mtile = co >> 4, l15 = co & 15;
  int ks = k >> 5, kk = k & 31, quad = kk >> 3, j = kk & 7;
  size_t off = ((size_t)((mtile * 24 + ks) * 64) + quad * 16 + l15) * 8 + j;
  WE[off] = (_Float16)we;
  WO[off] = (_Float16)wo;
}

// ---------------- fused conv GEMM: 8 waves = 2m x 2n x {E,O} ----------------
__launch_bounds__(512, 2)
__global__ void conv_gemm(const float* __restrict__ x,
                          const _Float16* __restrict__ WE,
                          const _Float16* __restrict__ WO,
                          float* __restrict__ out,
                          float* __restrict__ stats) {
  extern __shared__ char smem[];
  float*    sstats = (float*)smem;                 // [128][2] at offset 0
  _Float16* plane  = (_Float16*)(smem + 1024);     // [3][PCOLS][PCPAD]
  // epilogue exchange region reuses plane space (plane dead by then)

  const int tile = blockIdx.x;        // 0..63
  const int b    = blockIdx.y;        // 0..15
  const int i0   = tile * NT;
  const int t    = threadIdx.x;
  const int lane = t & 63;
  const int wave = t >> 6;            // 0..7
  const int p    = wave >> 1;         // wave-pair 0..3: 2x2 over (m,n)
  const int isO  = wave & 1;          // 0=Even outputs, 1=Odd outputs
  const int wm   = p >> 1, wn = p & 1;
  const int l15  = lane & 15, quad = lane >> 4;

  if (t < 128) { sstats[2 * t] = 0.f; sstats[2 * t + 1] = 0.f; }

  // --- build power planes: plane[q][col][c] = x[b,c,i0-1+col]^(q+1), fp16 ---
  // task = (col, c8-group): b128 writes (16B/lane, 272B lane-stride -> conflict-free)
  const float* xb = x + (size_t)b * CIN * LIN;
  for (int task = t; task < PCOLS * 16; task += 512) {
    int g   = task / PCOLS;                      // c-group 0..15
    int col = task - g * PCOLS;                  // consecutive t -> consecutive col (coalesced)
    int c8  = g * 8;
    int gi  = i0 - 1 + col;
    bool ok = (gi >= 0 && gi < LIN);
    f16x8 p1, p2, p3;
#pragma unroll
    for (int j = 0; j < 8; ++j) {
      float v = ok ? xb[(size_t)(c8 + j) * LIN + gi] : 0.f;
      float v2 = v * v;
      p1[j] = (_Float16)v;
      p2[j] = (_Float16)v2;
      p3[j] = (_Float16)(v2 * v);
    }
    _Float16* dst = plane + col * PCPAD + c8;
    *(f16x8*)(dst)           = p1;
    *(f16x8*)(dst + PSZ)     = p2;
    *(f16x8*)(dst + 2 * PSZ) = p3;
  }
  __syncthreads();

  f32x4 acc[4][4];
  const f32x4 zero = {0.f, 0.f, 0.f, 0.f};
#pragma unroll
  for (int fm = 0; fm < 4; ++fm)
#pragma unroll
    for (int fn = 0; fn < 4; ++fn) acc[fm][fn] = zero;

  const _Float16* Wsel = isO ? WO : WE;
  const int kl = quad * 8;

  // k-step ks -> (q, cb, sE): q=(ks%12)>>2, cb=(ks&3)*32, sE=(ks<12?0:1)
  // B col for this wave: wn*64 + fn*16 + l15 + sE + isO
  f16x8 af[2][4], bf[2][4];

#define LOAD_STEP(ks_, buf_)                                                        \
  {                                                                                 \
    const int q_  = ((ks_) % 12) >> 2;                                              \
    const int cb_ = ((ks_) & 3) * 32;                                               \
    const int sh_ = ((ks_) < 12 ? 0 : 1) + isO;                                     \
    const _Float16* pb_ = plane + q_ * PSZ + cb_ + kl;                              \
    _Pragma("unroll")                                                               \
    for (int fn = 0; fn < 4; ++fn) {                                                \
      int colB = wn * 64 + fn * 16 + l15 + sh_;                                     \
      bf[buf_][fn] = *(const f16x8*)(pb_ + colB * PCPAD);                           \
    }                                                                               \
    _Pragma("unroll")                                                               \
    for (int fm = 0; fm < 4; ++fm) {                                                \
      int mt = wm * 4 + fm;                                                         \
      af[buf_][fm] = *(const f16x8*)(Wsel + ((size_t)((mt * 24 + (ks_)) * 64) + lane) * 8); \
    }                                                                               \
  }

  LOAD_STEP(0, 0)
#pragma unroll
  for (int ks = 0; ks < 24; ++ks) {
    const int cur = ks & 1, nxt = cur ^ 1;
    if (ks < 23) LOAD_STEP(ks + 1, nxt)
#pragma unroll
    for (int fm = 0; fm < 4; ++fm)
#pragma unroll
      for (int fn = 0; fn < 4; ++fn)
        acc[fm][fn] = __builtin_amdgcn_mfma_f32_16x16x32_f16(af[cur][fm], bf[cur][fn], acc[fm][fn], 0, 0, 0);
  }
#undef LOAD_STEP

  // --- epilogue: O-waves hand acc to E-waves via LDS (plane region dead) ---
  __syncthreads();
  char* ex = smem + 1024 + p * (64 * 272) + lane * 272;   // 272B lane stride: conflict-free b128
  if (isO) {
#pragma unroll
    for (int fm = 0; fm < 4; ++fm)
#pragma unroll
      for (int fn = 0; fn < 4; ++fn)
        *(f32x4*)(ex + (fm * 4 + fn) * 16) = acc[fm][fn];
  }
  __syncthreads();

  if (!isO) {
    // C/D layout: n = lane&15, m = quad*4 + r
    float* orow_base = out + (size_t)b * COUT * LOUT;
#pragma unroll
    for (int fm = 0; fm < 4; ++fm) {
      f32x4 accO[4];
#pragma unroll
      for (int fn = 0; fn < 4; ++fn) accO[fn] = *(f32x4*)(ex + (fm * 4 + fn) * 16);
#pragma unroll
      for (int r = 0; r < 4; ++r) {
        float s1 = 0.f, s2 = 0.f;
#pragma unroll
        for (int fn = 0; fn < 4; ++fn) {
          float vE = acc[fm][fn][r], vO = accO[fn][r];
          s1 += vE + vO;
          s2 += vE * vE + vO * vO;
        }
#pragma unroll
        for (int off = 8; off >= 1; off >>= 1) {
          s1 += __shfl_xor(s1, off, 64);
          s2 += __shfl_xor(s2, off, 64);
        }
        int co = wm * 64 + fm * 16 + quad * 4 + r;
        if (l15 == 0) {
          atomicAdd(&sstats[2 * co], s1);
          atomicAdd(&sstats[2 * co + 1], s2);
        }
        float* orow = orow_base + (size_t)co * LOUT;
#pragma unroll
        for (int fn = 0; fn < 4; ++fn) {
          int n = i0 + wn * 64 + fn * 16 + l15;
          float2 v = make_float2(acc[fm][fn][r], accO[fn][r]);
          *(float2*)(orow + 2 * n) = v;   // even=E, odd=O, coalesced
        }
      }
    }
  }
  __syncthreads();
  if (t < 128) {
    atomicAdd(&stats[((size_t)b * COUT + t) * 2],     sstats[2 * t]);
    atomicAdd(&stats[((size_t)b * COUT + t) * 2 + 1], sstats[2 * t + 1]);
  }
}

// ---------------- instance norm + tanh, in place ----------------
__device__ inline float tanh_fast(float z) {
  float e = __expf(2.f * z);
  return 1.f - 2.f / (e + 1.f);
}

__global__ void norm_tanh(float* __restrict__ out, const float* __restrict__ stats) {
  int row = blockIdx.x;                         // b*128 + co
  float s1 = stats[2 * row], s2 = stats[2 * row + 1];
  const float invN = 1.f / (float)LOUT;
  float mean = s1 * invN;
  float var  = fmaxf(s2 * invN - mean * mean, 0.f);
  float inv  = rsqrtf(var + 1e-5f);
  float4* p = (float4*)(out + (size_t)row * LOUT);
  for (int i = threadIdx.x; i < LOUT / 4; i += 256) {
    float4 v = p[i];
    v.x = tanh_fast((v.x - mean) * inv);
    v.y = tanh_fast((v.y - mean) * inv);
    v.z = tanh_fast((v.z - mean) * inv);
    v.w = tanh_fast((v.w - mean) * inv);
    p[i] = v;
  }
}

extern "C" void kernel_launch(void* const* d_in, const int* in_sizes, int n_in,
                              void* d_out, int out_size, void* d_ws, size_t ws_size,
                              hipStream_t stream) {
  const float* x = (const float*)d_in[0];
  const float* W = (const float*)d_in[1];
  // bias (d_in[2]) is exactly cancelled by InstanceNorm -> unused
  float* out = (float*)d_out;

  float*    stats = (float*)d_ws;
  _Float16* WE    = (_Float16*)((char*)d_ws + 16384);
  _Float16* WO    = WE + (size_t)COUT * KEXP;

  hipMemsetAsync(d_ws, 0, 16384, stream);
  prep_weights<<<dim3((COUT * KEXP) / 256), dim3(256), 0, stream>>>(W, WE, WO);

  size_t shmem = 1024 + (size_t)3 * PSZ * 2;   // 107,104 B (exchange region fits inside)
  hipFuncSetAttribute(reinterpret_cast<const void*>(conv_gemm),
                      hipFuncAttributeMaxDynamicSharedMemorySize, (int)shmem);
  conv_gemm<<<dim3(NTILES, BATCH), dim3(512), shmem, stream>>>(x, WE, WO, out, stats);

  norm_tanh<<<dim3(BATCH * COUT), dim3(256), 0, stream>>>(out, stats);
}

// Round 4
// 312.229 us; speedup vs baseline: 1.4215x; 1.0523x over previous
//
#include <hip/hip_runtime.h>
#include <hip/hip_fp16.h>
#include <math.h>

#define BATCH 16
#define CIN   128
#define LIN   8192
#define COUT  128
#define LOUT  16384
#define KEXP  768          // 2 shift-halves * (3 powers * 128 channels)
#define NT    128          // i-tile width
#define NTILES (LIN/NT)    // 64
#define PCOLS 130          // i0-1 .. i0+128 inclusive
#define PCPAD 136          // halfwords per col; 272B stride, 16B aligned
#define PSZ   (PCOLS*PCPAD)  // one power plane: 17680 halfwords = 35360 B

typedef _Float16 f16x8 __attribute__((ext_vector_type(8)));
typedef float    f32x4 __attribute__((ext_vector_type(4)));

// ---------------- weight prep: fold taps, cast fp16, PHASE-MAJOR frag swizzle ----------------
// K-step order ks = q*8 + sh*4 + cb_idx  (q = power, sh = shift-half, cb = 32-chan group)
// Element (co,k) -> WE[((mtile*24 + ks)*64 + quad*16 + l15)*8 + j]
// so one A-frag load = uniform base + lane*16B (contiguous 1KB).
__global__ void prep_weights(const float* __restrict__ W,
                             _Float16* __restrict__ WE,
                             _Float16* __restrict__ WO) {
  int idx = blockIdx.x * 256 + threadIdx.x;       // 128*768 total
  int co = idx / KEXP;
  int k  = idx % KEXP;
  int sh = (k >= 384) ? 1 : 0;
  int cq = k - 384 * sh;                          // 384 is NOT a power of two
  const float* w = W + ((size_t)co * 384 + cq) * 3;
  float we, wo;
  if (sh == 0) { we = w[0];        wo = w[0] + w[1]; }
  else         { we = w[1] + w[2]; wo = w[2];        }
  int q  = cq >> 7;            // power plane 0..2
  int c  = cq & 127;           // channel within plane
  int ks = q * 8 + sh * 4 + (c >> 5);
  int kk = c & 31, quad = kk >> 3, j = kk & 7;
  int mtile = co >> 4, l15 = co & 15;
  size_t off = ((size_t)((mtile * 24 + ks) * 64) + quad * 16 + l15) * 8 + j;
  WE[off] = (_Float16)we;
  WO[off] = (_Float16)wo;
}

// ---------------- fused conv GEMM: 8 waves = 2m x 2n x {E,O}, phase-resident plane ----------------
__launch_bounds__(512, 4)
__global__ void conv_gemm(const float* __restrict__ x,
                          const _Float16* __restrict__ WE,
                          const _Float16* __restrict__ WO,
                          float* __restrict__ out,
                          float* __restrict__ stats) {
  extern __shared__ char smem[];
  float*    sstats = (float*)smem;                 // [128][2]
  _Float16* plane  = (_Float16*)(smem + 1024);     // [PCOLS][PCPAD] — ONE power at a time

  const int tile = blockIdx.x;        // 0..63
  const int b    = blockIdx.y;        // 0..15
  const int i0   = tile * NT;
  const int t    = threadIdx.x;
  const int lane = t & 63;
  const int wave = t >> 6;            // 0..7
  const int p    = wave >> 1;         // 2x2 over (m,n)
  const int isO  = wave & 1;          // 0=even outputs, 1=odd outputs
  const int wm   = p >> 1, wn = p & 1;
  const int l15  = lane & 15, quad = lane >> 4;
  const int kl   = quad * 8;

  if (t < 128) { sstats[2 * t] = 0.f; sstats[2 * t + 1] = 0.f; }

  const float* xb = x + (size_t)b * CIN * LIN;
  const _Float16* Wsel = isO ? WO : WE;

  f32x4 acc[4][4];
  const f32x4 zero = {0.f, 0.f, 0.f, 0.f};
#pragma unroll
  for (int fm = 0; fm < 4; ++fm)
#pragma unroll
    for (int fn = 0; fn < 4; ++fn) acc[fm][fn] = zero;

#pragma unroll
  for (int q = 0; q < 3; ++q) {
    // --- build plane q: plane[col][c] = x[b,c,i0-1+col]^(q+1), fp16, b128 writes ---
    for (int task = t; task < PCOLS * 16; task += 512) {
      int g   = task / PCOLS;                  // 8-channel group 0..15
      int col = task - g * PCOLS;              // consecutive t -> consecutive col (coalesced)
      int c8  = g * 8;
      int gi  = i0 - 1 + col;
      bool ok = (gi >= 0 && gi < LIN);
      f16x8 w;
#pragma unroll
      for (int j = 0; j < 8; ++j) {
        float v = ok ? xb[(size_t)(c8 + j) * LIN + gi] : 0.f;
        float pv = (q == 0) ? v : ((q == 1) ? v * v : v * v * v);
        w[j] = (_Float16)pv;
      }
      *(f16x8*)(plane + col * PCPAD + c8) = w;
    }
    __syncthreads();

    // --- 8 k-steps on this plane ---
#pragma unroll
    for (int s = 0; s < 8; ++s) {
      const int cb   = (s & 3) * 32;
      const int shft = (s >> 2) + isO;         // tap-half shift + odd offset
      const _Float16* pb = plane + cb + kl;
      f16x8 bf[4], af[4];
#pragma unroll
      for (int fn = 0; fn < 4; ++fn) {
        int colB = wn * 64 + fn * 16 + l15 + shft;
        bf[fn] = *(const f16x8*)(pb + colB * PCPAD);
      }
#pragma unroll
      for (int fm = 0; fm < 4; ++fm) {
        int mt = wm * 4 + fm;
        af[fm] = *(const f16x8*)(Wsel + ((size_t)((mt * 24 + q * 8 + s) * 64) + lane) * 8);
      }
#pragma unroll
      for (int fm = 0; fm < 4; ++fm)
#pragma unroll
        for (int fn = 0; fn < 4; ++fn)
          acc[fm][fn] = __builtin_amdgcn_mfma_f32_16x16x32_f16(af[fm], bf[fn], acc[fm][fn], 0, 0, 0);
    }
    __syncthreads();   // protect plane rebuild (q<2); harmless extra for q=2
  }

  // --- epilogue: per-wave stats + direct interleave-by-wave stores ---
  // C/D layout: n = lane&15, m = quad*4 + r
  float* orow_base = out + (size_t)b * COUT * LOUT + isO;
#pragma unroll
  for (int fm = 0; fm < 4; ++fm) {
#pragma unroll
    for (int r = 0; r < 4; ++r) {
      float s1 = 0.f, s2 = 0.f;
#pragma unroll
      for (int fn = 0; fn < 4; ++fn) {
        float v = acc[fm][fn][r];
        s1 += v;
        s2 += v * v;
      }
#pragma unroll
      for (int off = 8; off >= 1; off >>= 1) {   // reduce across the 16 n-lanes
        s1 += __shfl_xor(s1, off, 64);
        s2 += __shfl_xor(s2, off, 64);
      }
      int co = wm * 64 + fm * 16 + quad * 4 + r;
      if (l15 == 0) {
        atomicAdd(&sstats[2 * co], s1);
        atomicAdd(&sstats[2 * co + 1], s2);
      }
      float* orow = orow_base + (size_t)co * LOUT;
#pragma unroll
      for (int fn = 0; fn < 4; ++fn) {
        int n = i0 + wn * 64 + fn * 16 + l15;
        orow[2 * n] = acc[fm][fn][r];            // E/O waves write complementary 4B-interleave; L2 merges
      }
    }
  }
  __syncthreads();
  if (t < 128) {
    atomicAdd(&stats[((size_t)b * COUT + t) * 2],     sstats[2 * t]);
    atomicAdd(&stats[((size_t)b * COUT + t) * 2 + 1], sstats[2 * t + 1]);
  }
}

// ---------------- instance norm + tanh, in place ----------------
__device__ inline float tanh_fast(float z) {
  float e = __expf(2.f * z);
  return 1.f - 2.f * __builtin_amdgcn_rcpf(e + 1.f);  // v_rcp_f32: no fdiv slow-path
}

__global__ void norm_tanh(float* __restrict__ out, const float* __restrict__ stats) {
  int row = blockIdx.x;                         // b*128 + co
  float s1 = stats[2 * row], s2 = stats[2 * row + 1];
  const float invN = 1.f / (float)LOUT;
  float mean = s1 * invN;
  float var  = fmaxf(s2 * invN - mean * mean, 0.f);
  float inv  = rsqrtf(var + 1e-5f);
  float c0   = -mean * inv;
  float4* p = (float4*)(out + (size_t)row * LOUT);
  for (int i = threadIdx.x; i < LOUT / 4; i += 256) {
    float4 v = p[i];
    v.x = tanh_fast(fmaf(v.x, inv, c0));
    v.y = tanh_fast(fmaf(v.y, inv, c0));
    v.z = tanh_fast(fmaf(v.z, inv, c0));
    v.w = tanh_fast(fmaf(v.w, inv, c0));
    p[i] = v;
  }
}

extern "C" void kernel_launch(void* const* d_in, const int* in_sizes, int n_in,
                              void* d_out, int out_size, void* d_ws, size_t ws_size,
                              hipStream_t stream) {
  const float* x = (const float*)d_in[0];
  const float* W = (const float*)d_in[1];
  // bias (d_in[2]) is exactly cancelled by InstanceNorm -> unused
  float* out = (float*)d_out;

  float*    stats = (float*)d_ws;
  _Float16* WE    = (_Float16*)((char*)d_ws + 16384);
  _Float16* WO    = WE + (size_t)COUT * KEXP;

  hipMemsetAsync(d_ws, 0, 16384, stream);
  prep_weights<<<dim3((COUT * KEXP) / 256), dim3(256), 0, stream>>>(W, WE, WO);

  size_t shmem = 1024 + (size_t)PSZ * 2;   // 36,384 B -> LDS allows 4 blocks/CU; regs target 2
  hipFuncSetAttribute(reinterpret_cast<const void*>(conv_gemm),
                      hipFuncAttributeMaxDynamicSharedMemorySize, (int)shmem);
  conv_gemm<<<dim3(NTILES, BATCH), dim3(512), shmem, stream>>>(x, WE, WO, out, stats);

  norm_tanh<<<dim3(BATCH * COUT), dim3(256), 0, stream>>>(out, stats);
}